// Round 19
// baseline (61.348 us; speedup 1.0000x reference)
//
#include <hip/hip_runtime.h>
#include <math.h>
#include <stdint.h>

namespace {
constexpr int kB = 2, kN = 6, kC = 64, kD = 41, kH = 32, kW = 88;
constexpr int kHW = kH * kW;                  // 2816
constexpr int kBN = kB * kN;                  // 12
constexpr int kNX = 200;
constexpr int kVox = kNX * kNX;               // 40000
constexpr int kPts = kBN * kD * kHW;          // 1,385,472
constexpr int kRows4 = kB * kNX * 4;          // 1600 rows (b, ix, iy-quarter)
constexpr int kCap4 = 1120;                   // mean 866, +8.6 sigma
constexpr int kOvfCap = 4096;                 // overflow list (never used)

constexpr int kTiles = kBN * (kHW / 64);      // 528 (bn, hw-tile-64)
constexpr int kFusedBlks = kTiles * 2;        // [0,528) transpose | [528,1056) binfill
}  // namespace

// Blocks fp-contraction (hipcc -ffp-contract=fast would fuse mul+sub into
// fma and change voxel binning vs the per-op f32 numpy reference).
#define FP_BARRIER(x) asm volatile("" : "+v"(x))

// f32 -> bf16 with round-to-nearest-even (bf16 = high 16 bits of f32).
__device__ __forceinline__ uint32_t f2bf_rne(float f) {
  uint32_t u = __float_as_uint(f);
  return (u + 0x7FFFu + ((u >> 16) & 1u)) >> 16;
}

__device__ __forceinline__ float bf_lo(uint32_t u) {
  return __uint_as_float(u << 16);
}
__device__ __forceinline__ float bf_hi(uint32_t u) {
  return __uint_as_float(u & 0xFFFF0000u);
}

// Zero cnt[kRows4] + ovf_cnt (6.4KB). ~2us in the timed graph.
__global__ void __launch_bounds__(256) lss_zero(unsigned* __restrict__ cnt) {
  for (int i = threadIdx.x; i <= kRows4; i += 256) cnt[i] = 0u;
}

// Fused kernel, block-partitioned (identical to R18 passing version):
//   [0, kTiles)        : transpose feat [bn][c][hw] -> featT bf16 [bn*hw][32u32]
//   [kTiles, 2*kTiles) : per-(bn, hw-tile) softmax stats IN-BLOCK + voxel bin
//                        (proven barriered per-op f32) + row-CSR fill.
__global__ void __launch_bounds__(512) lss_fused(
    const float* __restrict__ feat, uint32_t* __restrict__ featT,
    const float* __restrict__ logits, const float* __restrict__ geom,
    unsigned* __restrict__ cnt, uint2* __restrict__ list,
    unsigned* __restrict__ ovf_cnt, uint4* __restrict__ ovf) {
  int blk = blockIdx.x;
  int tid = threadIdx.x;
  if (blk < kTiles) {
    // ---- transpose + bf16 pack ----
    __shared__ float t[64][65];
    int bn = blk / 44, hw0 = (blk % 44) * 64;
    const float* src = feat + (size_t)bn * kC * kHW;
    for (int idx = tid; idx < 64 * 64; idx += 512) {
      int c = idx >> 6, hw = idx & 63;           // consecutive tid -> hw
      t[hw][c] = src[(size_t)c * kHW + hw0 + hw];
    }
    __syncthreads();
    uint32_t* dst = featT + ((size_t)bn * kHW + hw0) * 32;
    for (int idx = tid; idx < 64 * 32; idx += 512) {
      int hw = idx >> 5, j = idx & 31;           // consecutive tid -> j
      uint32_t lo = f2bf_rne(t[hw][2 * j]);
      uint32_t hi = f2bf_rne(t[hw][2 * j + 1]);
      dst[(size_t)hw * 32 + j] = lo | (hi << 16);
    }
  } else {
    // ---- stats + bin + fill: tile (bn, hw0..hw0+63) x all d ----
    __shared__ unsigned shist[kRows4];   // 6.4K
    __shared__ unsigned sbase[kRows4];   // 6.4K
    __shared__ float smax[8 * 64];       // 2K
    __shared__ float ssum[8 * 64];       // 2K
    int tb = blk - kTiles;
    int bn = tb / 44, hw0 = (tb % 44) * 64;
    int hwl = tid & 63, dg = tid >> 6;   // 8 d-groups (waves)
    int hw = hw0 + hwl;
    int b = (bn >= kN) ? 1 : 0;
    int col = bn * kHW + hw;
    int d0 = (dg * kD) >> 3, d1 = ((dg + 1) * kD) >> 3;  // 5..6 d's each
    for (int r = tid; r < kRows4; r += 512) shist[r] = 0;
    // softmax stats (fmax exactly associative -> M identical to serial;
    // S differs ~1ulp from group-partial order -> harmless)
    float x[6];
    float m = -INFINITY;
#pragma unroll
    for (int k = 0; k < 6; ++k) {
      int d = d0 + k;
      if (d < d1) {
        x[k] = logits[(size_t)(bn * kD + d) * kHW + hw];
        m = fmaxf(m, x[k]);
      }
    }
    smax[dg * 64 + hwl] = m;
    __syncthreads();                      // also covers shist zeroing
    float M = smax[hwl];
#pragma unroll
    for (int gg = 1; gg < 8; ++gg) M = fmaxf(M, smax[gg * 64 + hwl]);
    float s = 0.0f;
#pragma unroll
    for (int k = 0; k < 6; ++k) {
      int d = d0 + k;
      if (d < d1) { x[k] = expf(x[k] - M); s += x[k]; }
    }
    ssum[dg * 64 + hwl] = s;
    __syncthreads();
    float S = ssum[hwl];
#pragma unroll
    for (int gg = 1; gg < 8; ++gg) S += ssum[gg * 64 + hwl];
    // voxel bin (proven barriered per-op f32) + per-row4 histogram
    int vv[6];
#pragma unroll
    for (int k = 0; k < 6; ++k) {
      vv[k] = -1;
      int d = d0 + k;
      if (d < d1) {
        size_t g = ((size_t)(bn * kD + d) * kHW + hw) * 3;
        float gx = geom[g + 0];
        float gy = geom[g + 1];
        float gz = geom[g + 2];
        float px = __fmul_rn(gx, 100.0f); FP_BARRIER(px);
        float py = __fmul_rn(gy, 100.0f); FP_BARRIER(py);
        float pz = __fmul_rn(gz, 20.0f);  FP_BARRIER(pz);
        float wx = __fsub_rn(px, 50.0f);  FP_BARRIER(wx);
        float wy = __fsub_rn(py, 50.0f);  FP_BARRIER(wy);
        float wz = __fsub_rn(pz, 10.0f);  FP_BARRIER(wz);
        float tx = __fadd_rn(wx, 50.0f);  FP_BARRIER(tx);
        float ty = __fadd_rn(wy, 50.0f);  FP_BARRIER(ty);
        float tz = __fadd_rn(wz, 10.0f);  FP_BARRIER(tz);
        float qx = __fdiv_rn(tx, 0.5f);   FP_BARRIER(qx);
        float qy = __fdiv_rn(ty, 0.5f);   FP_BARRIER(qy);
        float qz = __fdiv_rn(tz, 20.0f);  FP_BARRIER(qz);
        int ix = (int)floorf(qx);
        int iy = (int)floorf(qy);
        int iz = (int)floorf(qz);
        if ((unsigned)ix < (unsigned)kNX && (unsigned)iy < (unsigned)kNX &&
            (unsigned)iz < 1u) {
          vv[k] = (ix << 8) | iy;
          atomicAdd(&shist[((b * kNX + ix) << 2) + iy / 50], 1u);
        }
      }
    }
    __syncthreads();
    for (int r = tid; r < kRows4; r += 512)
      if (shist[r]) sbase[r] = atomicAdd(&cnt[r], shist[r]);
    __syncthreads();
    // scatter entries {iy|col, wgt} into fixed row segments (line-dense)
#pragma unroll
    for (int k = 0; k < 6; ++k) {
      if (vv[k] < 0) continue;
      int ix = vv[k] >> 8, iy = vv[k] & 255;
      int row4 = ((b * kNX + ix) << 2) + iy / 50;
      float wgt = x[k] / S;
      unsigned key = ((unsigned)iy << 16) | (unsigned)col;
      unsigned pos = atomicAdd(&sbase[row4], 1u);  // LDS cursor
      if (pos < (unsigned)kCap4) {
        list[(size_t)row4 * kCap4 + pos] =
            make_uint2(key, __float_as_uint(wgt));
      } else {                                     // never (+8.6 sigma)
        unsigned o = atomicAdd(ovf_cnt, 1u);
        if (o < (unsigned)kOvfCap)
          ovf[o] = make_uint4((unsigned)row4, key, __float_as_uint(wgt), 0u);
      }
    }
  }
}

// Row gather v6: 512 threads per (b, ix, iy-quarter).
// NEW vs R18: WAVE-PER-BIN accumulate — wave wv owns bins {wv, wv+8, ...}
// (R17/18's ly=tid>>3 left groups 50-63 idle (22%) and made each wave's
// trip count = max of 8 bins (~25% divergence)). Lane group ep = lane>>4
// processes entry k+ep; lane loads uint2 = 4 bf16 channels; 16-entry main
// iter = 4 loads in flight per lane; shfl_xor(16,32) reduce. Pass-1
// entries held in REGISTERS (3/thread) — no slr buffer, one global read.
__global__ void __launch_bounds__(512) lss_rowgather(
    const unsigned* __restrict__ cnt, const uint2* __restrict__ list,
    const uint32_t* __restrict__ featT, float* __restrict__ out,
    const unsigned* __restrict__ ovf_cnt, const uint4* __restrict__ ovf) {
  __shared__ uint2 sl[kCap4];           // 8.96 KB sorted entries
  __shared__ float accT[50 * 68];       // 13.6 KB (stride 68: float4-aligned)
  __shared__ unsigned hist[64];
  __shared__ unsigned off[51];
  __shared__ unsigned curb[50];
  int tid = threadIdx.x;
  // XCD swizzle: bijective (kRows4 % 8 == 0); XCD x gets r4 in [x*200,(x+1)*200)
  int r4 = ((blockIdx.x & 7) * (kRows4 / 8)) + (blockIdx.x >> 3);
  int q = r4 & 3;
  int r = r4 >> 2;
  int b = r / kNX, ix = r - (r / kNX) * kNX;
  int iyb = q * 50;
  size_t s0 = (size_t)r4 * kCap4;
  unsigned n = cnt[r4];
  unsigned ns = min(n, (unsigned)kCap4);

  if (tid < 64) hist[tid] = 0;
  __syncthreads();
  // pass 1: read entries into registers + histogram (one global read)
  uint2 e0, e1, e2;
  unsigned k0 = tid, k1 = tid + 512, k2 = tid + 1024;
  if (k0 < ns) { e0 = list[s0 + k0]; atomicAdd(&hist[(e0.x >> 16) - iyb], 1u); }
  if (k1 < ns) { e1 = list[s0 + k1]; atomicAdd(&hist[(e1.x >> 16) - iyb], 1u); }
  if (k2 < ns) { e2 = list[s0 + k2]; atomicAdd(&hist[(e2.x >> 16) - iyb], 1u); }
  __syncthreads();
  // wave-0 inclusive scan over 64 bins (no block barriers inside)
  if (tid < 64) {
    unsigned v = hist[tid];
    unsigned sc = v;
#pragma unroll
    for (int o = 1; o < 64; o <<= 1) {
      unsigned y = __shfl_up(sc, o);
      if (tid >= o) sc += y;
    }
    if (tid < 50) {
      off[tid] = sc - v;
      curb[tid] = sc - v;
    }
    if (tid == 0) off[50] = ns;
  }
  __syncthreads();
  // pass 2: scatter register-held entries into sorted LDS list
  if (k0 < ns) sl[atomicAdd(&curb[(e0.x >> 16) - iyb], 1u)] = e0;
  if (k1 < ns) sl[atomicAdd(&curb[(e1.x >> 16) - iyb], 1u)] = e1;
  if (k2 < ns) sl[atomicAdd(&curb[(e2.x >> 16) - iyb], 1u)] = e2;
  __syncthreads();
  // accumulate: wave wv owns bins {wv, wv+8, ...}; within a wave, group
  // ep = lane>>4 takes entry k+ep, lane covers channels (lane&15)*4..+3
  int wv = tid >> 6, lane = tid & 63;
  int ep = lane >> 4;
  int cu = (lane & 15) * 2;             // u32 offset into the 32-u32 row
  for (int ly = wv; ly < 50; ly += 8) {
    unsigned kk = off[ly], e = off[ly + 1];
    float a0 = 0, a1 = 0, a2 = 0, a3 = 0;
    // main: 16 entries per wave-uniform iteration, 4 loads in flight/lane
    for (; kk + 16 <= e; kk += 16) {
      unsigned k = kk + ep;
      uint2 x0 = sl[k];
      uint2 x1 = sl[k + 4];
      uint2 x2 = sl[k + 8];
      uint2 x3 = sl[k + 12];
      uint2 f0 = *(const uint2*)(featT + ((size_t)(x0.x & 0xFFFFu) << 5) + cu);
      uint2 f1 = *(const uint2*)(featT + ((size_t)(x1.x & 0xFFFFu) << 5) + cu);
      uint2 f2 = *(const uint2*)(featT + ((size_t)(x2.x & 0xFFFFu) << 5) + cu);
      uint2 f3 = *(const uint2*)(featT + ((size_t)(x3.x & 0xFFFFu) << 5) + cu);
      float w0 = __uint_as_float(x0.y), w1 = __uint_as_float(x1.y);
      float w2 = __uint_as_float(x2.y), w3 = __uint_as_float(x3.y);
      a0 += w0 * bf_lo(f0.x); a1 += w0 * bf_hi(f0.x);
      a2 += w0 * bf_lo(f0.y); a3 += w0 * bf_hi(f0.y);
      a0 += w1 * bf_lo(f1.x); a1 += w1 * bf_hi(f1.x);
      a2 += w1 * bf_lo(f1.y); a3 += w1 * bf_hi(f1.y);
      a0 += w2 * bf_lo(f2.x); a1 += w2 * bf_hi(f2.x);
      a2 += w2 * bf_lo(f2.y); a3 += w2 * bf_hi(f2.y);
      a0 += w3 * bf_lo(f3.x); a1 += w3 * bf_hi(f3.x);
      a2 += w3 * bf_lo(f3.y); a3 += w3 * bf_hi(f3.y);
    }
    // tail: 4 entries per pass (last pass partially masked)
    for (; kk < e; kk += 4) {
      unsigned k = kk + ep;
      if (k < e) {
        uint2 x0 = sl[k];
        uint2 f0 =
            *(const uint2*)(featT + ((size_t)(x0.x & 0xFFFFu) << 5) + cu);
        float w0 = __uint_as_float(x0.y);
        a0 += w0 * bf_lo(f0.x); a1 += w0 * bf_hi(f0.x);
        a2 += w0 * bf_lo(f0.y); a3 += w0 * bf_hi(f0.y);
      }
    }
    // butterfly reduce across the 4 ep groups (keeps lane&15)
    a0 += __shfl_xor(a0, 16); a0 += __shfl_xor(a0, 32);
    a1 += __shfl_xor(a1, 16); a1 += __shfl_xor(a1, 32);
    a2 += __shfl_xor(a2, 16); a2 += __shfl_xor(a2, 32);
    a3 += __shfl_xor(a3, 16); a3 += __shfl_xor(a3, 32);
    if (ep == 0) {
      float* dst = &accT[ly * 68 + (lane & 15) * 4];
      dst[0] = a0; dst[1] = a1; dst[2] = a2; dst[3] = a3;
    }
  }
  __syncthreads();
  // overflow epilogue (never taken; kept for correctness)
  unsigned ovfn = min(*ovf_cnt, (unsigned)kOvfCap);
  if (ovfn > 0) {
    for (unsigned k = tid; k < ovfn; k += 512) {
      uint4 a = ovf[k];
      if (a.x != (unsigned)r4) continue;
      int lyo = (int)(a.y >> 16) - iyb;
      const uint32_t* fr = featT + ((size_t)(a.y & 0xFFFFu) << 5);
      float w = __uint_as_float(a.z);
      for (int c = 0; c < kC; ++c) {
        uint32_t u = fr[c >> 1];
        float f = (c & 1) ? bf_hi(u) : bf_lo(u);
        atomicAdd(&accT[lyo * 68 + c], w * f);
      }
    }
    __syncthreads();
  }
  // coalesced tile store (every cell written -> no output memset)
  float* op = out + (size_t)b * kC * kVox + (size_t)ix * kNX + iyb;
  for (int idx = tid; idx < kC * 50; idx += 512) {
    int c = idx / 50, iy = idx - c * 50;
    op[(size_t)c * kVox + iy] = accT[iy * 68 + c];
  }
}

extern "C" void kernel_launch(void* const* d_in, const int* in_sizes, int n_in,
                              void* d_out, int out_size, void* d_ws,
                              size_t ws_size, hipStream_t stream) {
  const float* feat = (const float*)d_in[0];
  const float* logits = (const float*)d_in[1];
  const float* geom = (const float*)d_in[2];
  float* out = (float*)d_out;

  // Workspace layout (16B-aligned chunks): total ~18.7 MB
  char* w = (char*)d_ws;
  uint2* list = (uint2*)w;         w += (size_t)kRows4 * kCap4 * 8;  // 14.34MB
  uint32_t* featT = (uint32_t*)w;  w += (size_t)kBN * kHW * 32 * 4;  // 4.33MB
  uint4* ovf = (uint4*)w;          w += (size_t)kOvfCap * 16;        // 64KB
  unsigned* cnt = (unsigned*)w;    w += (size_t)kRows4 * 4;
  // ovf_cnt = cnt[kRows4] (zeroed together by lss_zero)
  unsigned* ovf_cnt = cnt + kRows4;

  lss_zero<<<1, 256, 0, stream>>>(cnt);
  lss_fused<<<kFusedBlks, 512, 0, stream>>>(feat, featT, logits, geom, cnt,
                                            list, ovf_cnt, ovf);
  lss_rowgather<<<kRows4, 512, 0, stream>>>(cnt, list, featT, out, ovf_cnt,
                                            ovf);
}

// Round 20
// 56.043 us; speedup vs baseline: 1.0947x; 1.0947x over previous
//
#include <hip/hip_runtime.h>
#include <math.h>
#include <stdint.h>

namespace {
constexpr int kB = 2, kN = 6, kC = 64, kD = 41, kH = 32, kW = 88;
constexpr int kHW = kH * kW;                  // 2816
constexpr int kBN = kB * kN;                  // 12
constexpr int kNX = 200;
constexpr int kVox = kNX * kNX;               // 40000
constexpr int kPts = kBN * kD * kHW;          // 1,385,472
constexpr int kRows4 = kB * kNX * 4;          // 1600 rows (b, ix, iy-quarter)
constexpr int kCap4 = 1120;                   // mean 866, +8.6 sigma
constexpr int kOvfCap = 4096;                 // overflow list (never used)

constexpr int kTiles = kBN * (kHW / 64);      // 528 (bn, hw-tile-64)
}  // namespace

// Blocks fp-contraction (hipcc -ffp-contract=fast would fuse mul+sub into
// fma and change voxel binning vs the per-op f32 numpy reference).
#define FP_BARRIER(x) asm volatile("" : "+v"(x))

// f32 -> bf16 with round-to-nearest-even (bf16 = high 16 bits of f32).
__device__ __forceinline__ uint32_t f2bf_rne(float f) {
  uint32_t u = __float_as_uint(f);
  return (u + 0x7FFFu + ((u >> 16) & 1u)) >> 16;
}

// Zero cnt[kRows4] + ovf_cnt (6.4KB). ~2us in the timed graph.
__global__ void __launch_bounds__(256) lss_zero(unsigned* __restrict__ cnt) {
  for (int i = threadIdx.x; i <= kRows4; i += 256) cnt[i] = 0u;
}

// Fused kernel v2: ONE block per (bn, hw-tile-64) does BOTH phases:
//   phase 1: transpose feat tile -> featT bf16 (same tile indices)
//   phase 2: softmax stats in-block + voxel bin (proven barriered per-op
//            f32) + row-CSR fill.
// vs R18: halves the grid (528 vs 1056 blocks -> less tail/launch), and
// the reservation scan start rotates with blk to decorrelate the global
// atomicAdd bursts (528 blocks no longer hit rows tid..tid+512 in lockstep).
__global__ void __launch_bounds__(512) lss_fused(
    const float* __restrict__ feat, uint32_t* __restrict__ featT,
    const float* __restrict__ logits, const float* __restrict__ geom,
    unsigned* __restrict__ cnt, uint2* __restrict__ list,
    unsigned* __restrict__ ovf_cnt, uint4* __restrict__ ovf) {
  __shared__ float t[64][65];          // 16.6K (phase 1 only)
  __shared__ unsigned shist[kRows4];   // 6.4K
  __shared__ unsigned sbase[kRows4];   // 6.4K
  __shared__ float smax[8 * 64];       // 2K
  __shared__ float ssum[8 * 64];       // 2K
  int blk = blockIdx.x;
  int tid = threadIdx.x;
  int bn = blk / 44, hw0 = (blk % 44) * 64;

  // ---- phase 1: transpose + bf16 pack ----
  const float* src = feat + (size_t)bn * kC * kHW;
  for (int idx = tid; idx < 64 * 64; idx += 512) {
    int c = idx >> 6, hw = idx & 63;             // consecutive tid -> hw
    t[hw][c] = src[(size_t)c * kHW + hw0 + hw];
  }
  __syncthreads();
  uint32_t* dst = featT + ((size_t)bn * kHW + hw0) * 32;
  for (int idx = tid; idx < 64 * 32; idx += 512) {
    int hw = idx >> 5, j = idx & 31;             // consecutive tid -> j
    uint32_t lo = f2bf_rne(t[hw][2 * j]);
    uint32_t hi = f2bf_rne(t[hw][2 * j + 1]);
    dst[(size_t)hw * 32 + j] = lo | (hi << 16);
  }

  // ---- phase 2: stats + bin + fill ----
  int hwl = tid & 63, dg = tid >> 6;   // 8 d-groups (waves)
  int hw = hw0 + hwl;
  int b = (bn >= kN) ? 1 : 0;
  int col = bn * kHW + hw;
  int d0 = (dg * kD) >> 3, d1 = ((dg + 1) * kD) >> 3;  // 5..6 d's each
  for (int r = tid; r < kRows4; r += 512) shist[r] = 0;
  // softmax stats (fmax exactly associative -> M identical to serial;
  // S differs ~1ulp from group-partial order -> harmless)
  float x[6];
  float m = -INFINITY;
#pragma unroll
  for (int k = 0; k < 6; ++k) {
    int d = d0 + k;
    if (d < d1) {
      x[k] = logits[(size_t)(bn * kD + d) * kHW + hw];
      m = fmaxf(m, x[k]);
    }
  }
  smax[dg * 64 + hwl] = m;
  __syncthreads();                      // covers shist zeroing + phase-1 LDS
  float M = smax[hwl];
#pragma unroll
  for (int gg = 1; gg < 8; ++gg) M = fmaxf(M, smax[gg * 64 + hwl]);
  float s = 0.0f;
#pragma unroll
  for (int k = 0; k < 6; ++k) {
    int d = d0 + k;
    if (d < d1) { x[k] = expf(x[k] - M); s += x[k]; }
  }
  ssum[dg * 64 + hwl] = s;
  __syncthreads();
  float S = ssum[hwl];
#pragma unroll
  for (int gg = 1; gg < 8; ++gg) S += ssum[gg * 64 + hwl];
  // voxel bin (proven barriered per-op f32) + per-row4 histogram
  int vv[6];
#pragma unroll
  for (int k = 0; k < 6; ++k) {
    vv[k] = -1;
    int d = d0 + k;
    if (d < d1) {
      size_t g = ((size_t)(bn * kD + d) * kHW + hw) * 3;
      float gx = geom[g + 0];
      float gy = geom[g + 1];
      float gz = geom[g + 2];
      float px = __fmul_rn(gx, 100.0f); FP_BARRIER(px);
      float py = __fmul_rn(gy, 100.0f); FP_BARRIER(py);
      float pz = __fmul_rn(gz, 20.0f);  FP_BARRIER(pz);
      float wx = __fsub_rn(px, 50.0f);  FP_BARRIER(wx);
      float wy = __fsub_rn(py, 50.0f);  FP_BARRIER(wy);
      float wz = __fsub_rn(pz, 10.0f);  FP_BARRIER(wz);
      float tx = __fadd_rn(wx, 50.0f);  FP_BARRIER(tx);
      float ty = __fadd_rn(wy, 50.0f);  FP_BARRIER(ty);
      float tz = __fadd_rn(wz, 10.0f);  FP_BARRIER(tz);
      float qx = __fdiv_rn(tx, 0.5f);   FP_BARRIER(qx);
      float qy = __fdiv_rn(ty, 0.5f);   FP_BARRIER(qy);
      float qz = __fdiv_rn(tz, 20.0f);  FP_BARRIER(qz);
      int ix = (int)floorf(qx);
      int iy = (int)floorf(qy);
      int iz = (int)floorf(qz);
      if ((unsigned)ix < (unsigned)kNX && (unsigned)iy < (unsigned)kNX &&
          (unsigned)iz < 1u) {
        vv[k] = (ix << 8) | iy;
        atomicAdd(&shist[((b * kNX + ix) << 2) + iy / 50], 1u);
      }
    }
  }
  __syncthreads();
  // global reservation, scan start rotated per block (decorrelate atomics)
  int off0 = (blk * 7) % kRows4;
  for (int rr = tid; rr < kRows4; rr += 512) {
    int r = rr + off0;
    if (r >= kRows4) r -= kRows4;
    if (shist[r]) sbase[r] = atomicAdd(&cnt[r], shist[r]);
  }
  __syncthreads();
  // scatter entries {iy|col, wgt} into fixed row segments (line-dense)
#pragma unroll
  for (int k = 0; k < 6; ++k) {
    if (vv[k] < 0) continue;
    int ix = vv[k] >> 8, iy = vv[k] & 255;
    int row4 = ((b * kNX + ix) << 2) + iy / 50;
    float wgt = x[k] / S;
    unsigned key = ((unsigned)iy << 16) | (unsigned)col;
    unsigned pos = atomicAdd(&sbase[row4], 1u);  // LDS cursor
    if (pos < (unsigned)kCap4) {
      list[(size_t)row4 * kCap4 + pos] = make_uint2(key, __float_as_uint(wgt));
    } else {                                     // never (+8.6 sigma)
      unsigned o = atomicAdd(ovf_cnt, 1u);
      if (o < (unsigned)kOvfCap)
        ovf[o] = make_uint4((unsigned)row4, key, __float_as_uint(wgt), 0u);
    }
  }
}

// Row gather: EXACT R18 v5 (proven 53.6us total). 512 threads per
// (b, ix, iy-quarter); XCD swizzle; single global pass (slr stash +
// wave-0 shfl scan); 8-lane group per bin, uint4 loads, 4-deep unroll.
__global__ void __launch_bounds__(512) lss_rowgather(
    const unsigned* __restrict__ cnt, const uint2* __restrict__ list,
    const uint32_t* __restrict__ featT, float* __restrict__ out,
    const unsigned* __restrict__ ovf_cnt, const uint4* __restrict__ ovf) {
  __shared__ uint2 slr[kCap4];          // 8.96 KB raw entries (arrival order)
  __shared__ uint2 sl[kCap4];           // 8.96 KB sorted entries
  __shared__ float accT[50 * 65];       // 13.0 KB (pad 65: store bank-free)
  __shared__ unsigned hist[64];
  __shared__ unsigned off[51];
  __shared__ unsigned curb[50];
  int tid = threadIdx.x;
  // XCD swizzle: bijective (kRows4 % 8 == 0); XCD x gets r4 in [x*200,(x+1)*200)
  int r4 = ((blockIdx.x & 7) * (kRows4 / 8)) + (blockIdx.x >> 3);
  int q = r4 & 3;
  int r = r4 >> 2;
  int b = r / kNX, ix = r - (r / kNX) * kNX;
  int iyb = q * 50;
  size_t s0 = (size_t)r4 * kCap4;
  unsigned n = cnt[r4];
  unsigned ns = min(n, (unsigned)kCap4);

  if (tid < 64) hist[tid] = 0;
  __syncthreads();
  // pass 1: stash + histogram (single global read of the row's entries)
  for (unsigned k = tid; k < ns; k += 512) {
    uint2 a = list[s0 + k];
    slr[k] = a;
    atomicAdd(&hist[(a.x >> 16) - iyb], 1u);
  }
  __syncthreads();
  // wave-0 inclusive scan over 64 bins (no block barriers inside)
  if (tid < 64) {
    unsigned v = hist[tid];
    unsigned sc = v;
#pragma unroll
    for (int o = 1; o < 64; o <<= 1) {
      unsigned y = __shfl_up(sc, o);
      if (tid >= o) sc += y;
    }
    if (tid < 50) {
      off[tid] = sc - v;
      curb[tid] = sc - v;
    }
    if (tid == 0) off[50] = ns;
  }
  __syncthreads();
  // pass 2: reorder LDS -> LDS (no second global read)
  for (unsigned k = tid; k < ns; k += 512) {
    uint2 a = slr[k];
    unsigned pos = atomicAdd(&curb[(a.x >> 16) - iyb], 1u);
    sl[pos] = a;
  }
  __syncthreads();
  // accumulate: group ly = tid>>3 owns bin ly; lane sub = tid&7 owns
  // channels sub*8..sub*8+7 (uint4 = 4 u32 = 8 bf16)
  int ly = tid >> 3, sub = tid & 7;
  if (ly < 50) {
    unsigned k = off[ly], e = off[ly + 1];
    float a0 = 0, a1 = 0, a2 = 0, a3 = 0, a4 = 0, a5 = 0, a6 = 0, a7 = 0;
    for (; k + 4 <= e; k += 4) {        // 4 entries -> 4 lines in flight
      uint2 e0 = sl[k + 0];
      uint2 e1 = sl[k + 1];
      uint2 e2 = sl[k + 2];
      uint2 e3 = sl[k + 3];
      uint4 f0 = ((const uint4*)(featT + ((size_t)(e0.x & 0xFFFFu) << 5)))[sub];
      uint4 f1 = ((const uint4*)(featT + ((size_t)(e1.x & 0xFFFFu) << 5)))[sub];
      uint4 f2 = ((const uint4*)(featT + ((size_t)(e2.x & 0xFFFFu) << 5)))[sub];
      uint4 f3 = ((const uint4*)(featT + ((size_t)(e3.x & 0xFFFFu) << 5)))[sub];
      float w0 = __uint_as_float(e0.y), w1 = __uint_as_float(e1.y);
      float w2 = __uint_as_float(e2.y), w3 = __uint_as_float(e3.y);
      a0 += w0 * __uint_as_float(f0.x << 16);
      a1 += w0 * __uint_as_float(f0.x & 0xFFFF0000u);
      a2 += w0 * __uint_as_float(f0.y << 16);
      a3 += w0 * __uint_as_float(f0.y & 0xFFFF0000u);
      a4 += w0 * __uint_as_float(f0.z << 16);
      a5 += w0 * __uint_as_float(f0.z & 0xFFFF0000u);
      a6 += w0 * __uint_as_float(f0.w << 16);
      a7 += w0 * __uint_as_float(f0.w & 0xFFFF0000u);
      a0 += w1 * __uint_as_float(f1.x << 16);
      a1 += w1 * __uint_as_float(f1.x & 0xFFFF0000u);
      a2 += w1 * __uint_as_float(f1.y << 16);
      a3 += w1 * __uint_as_float(f1.y & 0xFFFF0000u);
      a4 += w1 * __uint_as_float(f1.z << 16);
      a5 += w1 * __uint_as_float(f1.z & 0xFFFF0000u);
      a6 += w1 * __uint_as_float(f1.w << 16);
      a7 += w1 * __uint_as_float(f1.w & 0xFFFF0000u);
      a0 += w2 * __uint_as_float(f2.x << 16);
      a1 += w2 * __uint_as_float(f2.x & 0xFFFF0000u);
      a2 += w2 * __uint_as_float(f2.y << 16);
      a3 += w2 * __uint_as_float(f2.y & 0xFFFF0000u);
      a4 += w2 * __uint_as_float(f2.z << 16);
      a5 += w2 * __uint_as_float(f2.z & 0xFFFF0000u);
      a6 += w2 * __uint_as_float(f2.w << 16);
      a7 += w2 * __uint_as_float(f2.w & 0xFFFF0000u);
      a0 += w3 * __uint_as_float(f3.x << 16);
      a1 += w3 * __uint_as_float(f3.x & 0xFFFF0000u);
      a2 += w3 * __uint_as_float(f3.y << 16);
      a3 += w3 * __uint_as_float(f3.y & 0xFFFF0000u);
      a4 += w3 * __uint_as_float(f3.z << 16);
      a5 += w3 * __uint_as_float(f3.z & 0xFFFF0000u);
      a6 += w3 * __uint_as_float(f3.w << 16);
      a7 += w3 * __uint_as_float(f3.w & 0xFFFF0000u);
    }
    for (; k < e; ++k) {
      uint2 ea = sl[k];
      uint4 fa = ((const uint4*)(featT + ((size_t)(ea.x & 0xFFFFu) << 5)))[sub];
      float wa = __uint_as_float(ea.y);
      a0 += wa * __uint_as_float(fa.x << 16);
      a1 += wa * __uint_as_float(fa.x & 0xFFFF0000u);
      a2 += wa * __uint_as_float(fa.y << 16);
      a3 += wa * __uint_as_float(fa.y & 0xFFFF0000u);
      a4 += wa * __uint_as_float(fa.z << 16);
      a5 += wa * __uint_as_float(fa.z & 0xFFFF0000u);
      a6 += wa * __uint_as_float(fa.w << 16);
      a7 += wa * __uint_as_float(fa.w & 0xFFFF0000u);
    }
    float* dst = &accT[ly * 65 + (sub << 3)];
    dst[0] = a0; dst[1] = a1; dst[2] = a2; dst[3] = a3;
    dst[4] = a4; dst[5] = a5; dst[6] = a6; dst[7] = a7;
  }
  __syncthreads();
  // overflow epilogue (never taken; kept for correctness)
  unsigned ovfn = min(*ovf_cnt, (unsigned)kOvfCap);
  if (ovfn > 0) {
    for (unsigned k = tid; k < ovfn; k += 512) {
      uint4 a = ovf[k];
      if (a.x != (unsigned)r4) continue;
      int lyo = (int)(a.y >> 16) - iyb;
      const uint32_t* fr = featT + ((size_t)(a.y & 0xFFFFu) << 5);
      float w = __uint_as_float(a.z);
      for (int c = 0; c < kC; ++c) {
        uint32_t u = fr[c >> 1];
        float f = __uint_as_float((c & 1) ? (u & 0xFFFF0000u) : (u << 16));
        atomicAdd(&accT[lyo * 65 + c], w * f);
      }
    }
    __syncthreads();
  }
  // coalesced tile store (every cell written -> no output memset)
  float* op = out + (size_t)b * kC * kVox + (size_t)ix * kNX + iyb;
  for (int idx = tid; idx < kC * 50; idx += 512) {
    int c = idx / 50, iy = idx - c * 50;
    op[(size_t)c * kVox + iy] = accT[iy * 65 + c];
  }
}

extern "C" void kernel_launch(void* const* d_in, const int* in_sizes, int n_in,
                              void* d_out, int out_size, void* d_ws,
                              size_t ws_size, hipStream_t stream) {
  const float* feat = (const float*)d_in[0];
  const float* logits = (const float*)d_in[1];
  const float* geom = (const float*)d_in[2];
  float* out = (float*)d_out;

  // Workspace layout (16B-aligned chunks): total ~18.7 MB
  char* w = (char*)d_ws;
  uint2* list = (uint2*)w;         w += (size_t)kRows4 * kCap4 * 8;  // 14.34MB
  uint32_t* featT = (uint32_t*)w;  w += (size_t)kBN * kHW * 32 * 4;  // 4.33MB
  uint4* ovf = (uint4*)w;          w += (size_t)kOvfCap * 16;        // 64KB
  unsigned* cnt = (unsigned*)w;    w += (size_t)kRows4 * 4;
  // ovf_cnt = cnt[kRows4] (zeroed together by lss_zero)
  unsigned* ovf_cnt = cnt + kRows4;

  lss_zero<<<1, 256, 0, stream>>>(cnt);
  lss_fused<<<kTiles, 512, 0, stream>>>(feat, featT, logits, geom, cnt,
                                        list, ovf_cnt, ovf);
  lss_rowgather<<<kRows4, 512, 0, stream>>>(cnt, list, featT, out, ovf_cnt,
                                            ovf);
}

// Round 21
// 55.284 us; speedup vs baseline: 1.1097x; 1.0137x over previous
//
#include <hip/hip_runtime.h>
#include <math.h>
#include <stdint.h>

namespace {
constexpr int kB = 2, kN = 6, kC = 64, kD = 41, kH = 32, kW = 88;
constexpr int kHW = kH * kW;                  // 2816
constexpr int kBN = kB * kN;                  // 12
constexpr int kNX = 200;
constexpr int kVox = kNX * kNX;               // 40000
constexpr int kPts = kBN * kD * kHW;          // 1,385,472
constexpr int kRows4 = kB * kNX * 4;          // 1600 rows (b, ix, iy-quarter)
constexpr int kCap4 = 1120;                   // mean 866, +8.6 sigma
constexpr int kOvfCap = 4096;                 // overflow list (never used)

constexpr int kTiles = kBN * (kHW / 64);      // 528 (bn, hw-tile-64)
constexpr int kFusedBlks = kTiles * 2;        // [0,528) transpose | [528,1056) binfill
}  // namespace

// Blocks fp-contraction (hipcc -ffp-contract=fast would fuse mul+sub into
// fma and change voxel binning vs the per-op f32 numpy reference).
#define FP_BARRIER(x) asm volatile("" : "+v"(x))

// f32 -> bf16 with round-to-nearest-even (bf16 = high 16 bits of f32).
__device__ __forceinline__ uint32_t f2bf_rne(float f) {
  uint32_t u = __float_as_uint(f);
  return (u + 0x7FFFu + ((u >> 16) & 1u)) >> 16;
}

// Zero cnt[kRows4] + ovf_cnt (6.4KB). ~2us in the timed graph.
__global__ void __launch_bounds__(256) lss_zero(unsigned* __restrict__ cnt) {
  for (int i = threadIdx.x; i <= kRows4; i += 256) cnt[i] = 0u;
}

// Fused kernel, block-partitioned (EXACT R18 structure — best measured):
//   [0, kTiles)        : transpose feat [bn][c][hw] -> featT bf16 [bn*hw][32u32]
//   [kTiles, 2*kTiles) : per-(bn, hw-tile) softmax stats IN-BLOCK + voxel bin
//                        (proven barriered per-op f32) + row-CSR fill.
// Only change vs R18: reservation-scan start rotates with blk to
// decorrelate the 528 blocks' global atomicAdd bursts on cnt.
__global__ void __launch_bounds__(512) lss_fused(
    const float* __restrict__ feat, uint32_t* __restrict__ featT,
    const float* __restrict__ logits, const float* __restrict__ geom,
    unsigned* __restrict__ cnt, uint2* __restrict__ list,
    unsigned* __restrict__ ovf_cnt, uint4* __restrict__ ovf) {
  int blk = blockIdx.x;
  int tid = threadIdx.x;
  if (blk < kTiles) {
    // ---- transpose + bf16 pack ----
    __shared__ float t[64][65];
    int bn = blk / 44, hw0 = (blk % 44) * 64;
    const float* src = feat + (size_t)bn * kC * kHW;
    for (int idx = tid; idx < 64 * 64; idx += 512) {
      int c = idx >> 6, hw = idx & 63;           // consecutive tid -> hw
      t[hw][c] = src[(size_t)c * kHW + hw0 + hw];
    }
    __syncthreads();
    uint32_t* dst = featT + ((size_t)bn * kHW + hw0) * 32;
    for (int idx = tid; idx < 64 * 32; idx += 512) {
      int hw = idx >> 5, j = idx & 31;           // consecutive tid -> j
      uint32_t lo = f2bf_rne(t[hw][2 * j]);
      uint32_t hi = f2bf_rne(t[hw][2 * j + 1]);
      dst[(size_t)hw * 32 + j] = lo | (hi << 16);
    }
  } else {
    // ---- stats + bin + fill: tile (bn, hw0..hw0+63) x all d ----
    __shared__ unsigned shist[kRows4];   // 6.4K
    __shared__ unsigned sbase[kRows4];   // 6.4K
    __shared__ float smax[8 * 64];       // 2K
    __shared__ float ssum[8 * 64];       // 2K
    int tb = blk - kTiles;
    int bn = tb / 44, hw0 = (tb % 44) * 64;
    int hwl = tid & 63, dg = tid >> 6;   // 8 d-groups (waves)
    int hw = hw0 + hwl;
    int b = (bn >= kN) ? 1 : 0;
    int col = bn * kHW + hw;
    int d0 = (dg * kD) >> 3, d1 = ((dg + 1) * kD) >> 3;  // 5..6 d's each
    for (int r = tid; r < kRows4; r += 512) shist[r] = 0;
    // softmax stats (fmax exactly associative -> M identical to serial;
    // S differs ~1ulp from group-partial order -> harmless)
    float x[6];
    float m = -INFINITY;
#pragma unroll
    for (int k = 0; k < 6; ++k) {
      int d = d0 + k;
      if (d < d1) {
        x[k] = logits[(size_t)(bn * kD + d) * kHW + hw];
        m = fmaxf(m, x[k]);
      }
    }
    smax[dg * 64 + hwl] = m;
    __syncthreads();                      // also covers shist zeroing
    float M = smax[hwl];
#pragma unroll
    for (int gg = 1; gg < 8; ++gg) M = fmaxf(M, smax[gg * 64 + hwl]);
    float s = 0.0f;
#pragma unroll
    for (int k = 0; k < 6; ++k) {
      int d = d0 + k;
      if (d < d1) { x[k] = expf(x[k] - M); s += x[k]; }
    }
    ssum[dg * 64 + hwl] = s;
    __syncthreads();
    float S = ssum[hwl];
#pragma unroll
    for (int gg = 1; gg < 8; ++gg) S += ssum[gg * 64 + hwl];
    // voxel bin (proven barriered per-op f32) + per-row4 histogram
    int vv[6];
#pragma unroll
    for (int k = 0; k < 6; ++k) {
      vv[k] = -1;
      int d = d0 + k;
      if (d < d1) {
        size_t g = ((size_t)(bn * kD + d) * kHW + hw) * 3;
        float gx = geom[g + 0];
        float gy = geom[g + 1];
        float gz = geom[g + 2];
        float px = __fmul_rn(gx, 100.0f); FP_BARRIER(px);
        float py = __fmul_rn(gy, 100.0f); FP_BARRIER(py);
        float pz = __fmul_rn(gz, 20.0f);  FP_BARRIER(pz);
        float wx = __fsub_rn(px, 50.0f);  FP_BARRIER(wx);
        float wy = __fsub_rn(py, 50.0f);  FP_BARRIER(wy);
        float wz = __fsub_rn(pz, 10.0f);  FP_BARRIER(wz);
        float tx = __fadd_rn(wx, 50.0f);  FP_BARRIER(tx);
        float ty = __fadd_rn(wy, 50.0f);  FP_BARRIER(ty);
        float tz = __fadd_rn(wz, 10.0f);  FP_BARRIER(tz);
        float qx = __fdiv_rn(tx, 0.5f);   FP_BARRIER(qx);
        float qy = __fdiv_rn(ty, 0.5f);   FP_BARRIER(qy);
        float qz = __fdiv_rn(tz, 20.0f);  FP_BARRIER(qz);
        int ix = (int)floorf(qx);
        int iy = (int)floorf(qy);
        int iz = (int)floorf(qz);
        if ((unsigned)ix < (unsigned)kNX && (unsigned)iy < (unsigned)kNX &&
            (unsigned)iz < 1u) {
          vv[k] = (ix << 8) | iy;
          atomicAdd(&shist[((b * kNX + ix) << 2) + iy / 50], 1u);
        }
      }
    }
    __syncthreads();
    // global reservation, scan start rotated per block (decorrelate atomics)
    int off0 = (blk * 7) % kRows4;
    for (int rr = tid; rr < kRows4; rr += 512) {
      int r = rr + off0;
      if (r >= kRows4) r -= kRows4;
      if (shist[r]) sbase[r] = atomicAdd(&cnt[r], shist[r]);
    }
    __syncthreads();
    // scatter entries {iy|col, wgt} into fixed row segments (line-dense)
#pragma unroll
    for (int k = 0; k < 6; ++k) {
      if (vv[k] < 0) continue;
      int ix = vv[k] >> 8, iy = vv[k] & 255;
      int row4 = ((b * kNX + ix) << 2) + iy / 50;
      float wgt = x[k] / S;
      unsigned key = ((unsigned)iy << 16) | (unsigned)col;
      unsigned pos = atomicAdd(&sbase[row4], 1u);  // LDS cursor
      if (pos < (unsigned)kCap4) {
        list[(size_t)row4 * kCap4 + pos] =
            make_uint2(key, __float_as_uint(wgt));
      } else {                                     // never (+8.6 sigma)
        unsigned o = atomicAdd(ovf_cnt, 1u);
        if (o < (unsigned)kOvfCap)
          ovf[o] = make_uint4((unsigned)row4, key, __float_as_uint(wgt), 0u);
      }
    }
  }
}

// Row gather: EXACT R18 v5 (best measured). 512 threads per
// (b, ix, iy-quarter); XCD swizzle; single global pass (slr stash +
// wave-0 shfl scan); 8-lane group per bin, uint4 loads, 4-deep unroll.
__global__ void __launch_bounds__(512) lss_rowgather(
    const unsigned* __restrict__ cnt, const uint2* __restrict__ list,
    const uint32_t* __restrict__ featT, float* __restrict__ out,
    const unsigned* __restrict__ ovf_cnt, const uint4* __restrict__ ovf) {
  __shared__ uint2 slr[kCap4];          // 8.96 KB raw entries (arrival order)
  __shared__ uint2 sl[kCap4];           // 8.96 KB sorted entries
  __shared__ float accT[50 * 65];       // 13.0 KB (pad 65: store bank-free)
  __shared__ unsigned hist[64];
  __shared__ unsigned off[51];
  __shared__ unsigned curb[50];
  int tid = threadIdx.x;
  // XCD swizzle: bijective (kRows4 % 8 == 0); XCD x gets r4 in [x*200,(x+1)*200)
  int r4 = ((blockIdx.x & 7) * (kRows4 / 8)) + (blockIdx.x >> 3);
  int q = r4 & 3;
  int r = r4 >> 2;
  int b = r / kNX, ix = r - (r / kNX) * kNX;
  int iyb = q * 50;
  size_t s0 = (size_t)r4 * kCap4;
  unsigned n = cnt[r4];
  unsigned ns = min(n, (unsigned)kCap4);

  if (tid < 64) hist[tid] = 0;
  __syncthreads();
  // pass 1: stash + histogram (single global read of the row's entries)
  for (unsigned k = tid; k < ns; k += 512) {
    uint2 a = list[s0 + k];
    slr[k] = a;
    atomicAdd(&hist[(a.x >> 16) - iyb], 1u);
  }
  __syncthreads();
  // wave-0 inclusive scan over 64 bins (no block barriers inside)
  if (tid < 64) {
    unsigned v = hist[tid];
    unsigned sc = v;
#pragma unroll
    for (int o = 1; o < 64; o <<= 1) {
      unsigned y = __shfl_up(sc, o);
      if (tid >= o) sc += y;
    }
    if (tid < 50) {
      off[tid] = sc - v;
      curb[tid] = sc - v;
    }
    if (tid == 0) off[50] = ns;
  }
  __syncthreads();
  // pass 2: reorder LDS -> LDS (no second global read)
  for (unsigned k = tid; k < ns; k += 512) {
    uint2 a = slr[k];
    unsigned pos = atomicAdd(&curb[(a.x >> 16) - iyb], 1u);
    sl[pos] = a;
  }
  __syncthreads();
  // accumulate: group ly = tid>>3 owns bin ly; lane sub = tid&7 owns
  // channels sub*8..sub*8+7 (uint4 = 4 u32 = 8 bf16)
  int ly = tid >> 3, sub = tid & 7;
  if (ly < 50) {
    unsigned k = off[ly], e = off[ly + 1];
    float a0 = 0, a1 = 0, a2 = 0, a3 = 0, a4 = 0, a5 = 0, a6 = 0, a7 = 0;
    for (; k + 4 <= e; k += 4) {        // 4 entries -> 4 lines in flight
      uint2 e0 = sl[k + 0];
      uint2 e1 = sl[k + 1];
      uint2 e2 = sl[k + 2];
      uint2 e3 = sl[k + 3];
      uint4 f0 = ((const uint4*)(featT + ((size_t)(e0.x & 0xFFFFu) << 5)))[sub];
      uint4 f1 = ((const uint4*)(featT + ((size_t)(e1.x & 0xFFFFu) << 5)))[sub];
      uint4 f2 = ((const uint4*)(featT + ((size_t)(e2.x & 0xFFFFu) << 5)))[sub];
      uint4 f3 = ((const uint4*)(featT + ((size_t)(e3.x & 0xFFFFu) << 5)))[sub];
      float w0 = __uint_as_float(e0.y), w1 = __uint_as_float(e1.y);
      float w2 = __uint_as_float(e2.y), w3 = __uint_as_float(e3.y);
      a0 += w0 * __uint_as_float(f0.x << 16);
      a1 += w0 * __uint_as_float(f0.x & 0xFFFF0000u);
      a2 += w0 * __uint_as_float(f0.y << 16);
      a3 += w0 * __uint_as_float(f0.y & 0xFFFF0000u);
      a4 += w0 * __uint_as_float(f0.z << 16);
      a5 += w0 * __uint_as_float(f0.z & 0xFFFF0000u);
      a6 += w0 * __uint_as_float(f0.w << 16);
      a7 += w0 * __uint_as_float(f0.w & 0xFFFF0000u);
      a0 += w1 * __uint_as_float(f1.x << 16);
      a1 += w1 * __uint_as_float(f1.x & 0xFFFF0000u);
      a2 += w1 * __uint_as_float(f1.y << 16);
      a3 += w1 * __uint_as_float(f1.y & 0xFFFF0000u);
      a4 += w1 * __uint_as_float(f1.z << 16);
      a5 += w1 * __uint_as_float(f1.z & 0xFFFF0000u);
      a6 += w1 * __uint_as_float(f1.w << 16);
      a7 += w1 * __uint_as_float(f1.w & 0xFFFF0000u);
      a0 += w2 * __uint_as_float(f2.x << 16);
      a1 += w2 * __uint_as_float(f2.x & 0xFFFF0000u);
      a2 += w2 * __uint_as_float(f2.y << 16);
      a3 += w2 * __uint_as_float(f2.y & 0xFFFF0000u);
      a4 += w2 * __uint_as_float(f2.z << 16);
      a5 += w2 * __uint_as_float(f2.z & 0xFFFF0000u);
      a6 += w2 * __uint_as_float(f2.w << 16);
      a7 += w2 * __uint_as_float(f2.w & 0xFFFF0000u);
      a0 += w3 * __uint_as_float(f3.x << 16);
      a1 += w3 * __uint_as_float(f3.x & 0xFFFF0000u);
      a2 += w3 * __uint_as_float(f3.y << 16);
      a3 += w3 * __uint_as_float(f3.y & 0xFFFF0000u);
      a4 += w3 * __uint_as_float(f3.z << 16);
      a5 += w3 * __uint_as_float(f3.z & 0xFFFF0000u);
      a6 += w3 * __uint_as_float(f3.w << 16);
      a7 += w3 * __uint_as_float(f3.w & 0xFFFF0000u);
    }
    for (; k < e; ++k) {
      uint2 ea = sl[k];
      uint4 fa = ((const uint4*)(featT + ((size_t)(ea.x & 0xFFFFu) << 5)))[sub];
      float wa = __uint_as_float(ea.y);
      a0 += wa * __uint_as_float(fa.x << 16);
      a1 += wa * __uint_as_float(fa.x & 0xFFFF0000u);
      a2 += wa * __uint_as_float(fa.y << 16);
      a3 += wa * __uint_as_float(fa.y & 0xFFFF0000u);
      a4 += wa * __uint_as_float(fa.z << 16);
      a5 += wa * __uint_as_float(fa.z & 0xFFFF0000u);
      a6 += wa * __uint_as_float(fa.w << 16);
      a7 += wa * __uint_as_float(fa.w & 0xFFFF0000u);
    }
    float* dst = &accT[ly * 65 + (sub << 3)];
    dst[0] = a0; dst[1] = a1; dst[2] = a2; dst[3] = a3;
    dst[4] = a4; dst[5] = a5; dst[6] = a6; dst[7] = a7;
  }
  __syncthreads();
  // overflow epilogue (never taken; kept for correctness)
  unsigned ovfn = min(*ovf_cnt, (unsigned)kOvfCap);
  if (ovfn > 0) {
    for (unsigned k = tid; k < ovfn; k += 512) {
      uint4 a = ovf[k];
      if (a.x != (unsigned)r4) continue;
      int lyo = (int)(a.y >> 16) - iyb;
      const uint32_t* fr = featT + ((size_t)(a.y & 0xFFFFu) << 5);
      float w = __uint_as_float(a.z);
      for (int c = 0; c < kC; ++c) {
        uint32_t u = fr[c >> 1];
        float f = __uint_as_float((c & 1) ? (u & 0xFFFF0000u) : (u << 16));
        atomicAdd(&accT[lyo * 65 + c], w * f);
      }
    }
    __syncthreads();
  }
  // coalesced tile store (every cell written -> no output memset)
  float* op = out + (size_t)b * kC * kVox + (size_t)ix * kNX + iyb;
  for (int idx = tid; idx < kC * 50; idx += 512) {
    int c = idx / 50, iy = idx - c * 50;
    op[(size_t)c * kVox + iy] = accT[iy * 65 + c];
  }
}

extern "C" void kernel_launch(void* const* d_in, const int* in_sizes, int n_in,
                              void* d_out, int out_size, void* d_ws,
                              size_t ws_size, hipStream_t stream) {
  const float* feat = (const float*)d_in[0];
  const float* logits = (const float*)d_in[1];
  const float* geom = (const float*)d_in[2];
  float* out = (float*)d_out;

  // Workspace layout (16B-aligned chunks): total ~18.7 MB
  char* w = (char*)d_ws;
  uint2* list = (uint2*)w;         w += (size_t)kRows4 * kCap4 * 8;  // 14.34MB
  uint32_t* featT = (uint32_t*)w;  w += (size_t)kBN * kHW * 32 * 4;  // 4.33MB
  uint4* ovf = (uint4*)w;          w += (size_t)kOvfCap * 16;        // 64KB
  unsigned* cnt = (unsigned*)w;    w += (size_t)kRows4 * 4;
  // ovf_cnt = cnt[kRows4] (zeroed together by lss_zero)
  unsigned* ovf_cnt = cnt + kRows4;

  lss_zero<<<1, 256, 0, stream>>>(cnt);
  lss_fused<<<kFusedBlks, 512, 0, stream>>>(feat, featT, logits, geom, cnt,
                                            list, ovf_cnt, ovf);
  lss_rowgather<<<kRows4, 512, 0, stream>>>(cnt, list, featT, out, ovf_cnt,
                                            ovf);
}

// Round 22
// 53.207 us; speedup vs baseline: 1.1530x; 1.0390x over previous
//
#include <hip/hip_runtime.h>
#include <math.h>
#include <stdint.h>

namespace {
constexpr int kB = 2, kN = 6, kC = 64, kD = 41, kH = 32, kW = 88;
constexpr int kHW = kH * kW;                  // 2816
constexpr int kBN = kB * kN;                  // 12
constexpr int kNX = 200;
constexpr int kVox = kNX * kNX;               // 40000
constexpr int kPts = kBN * kD * kHW;          // 1,385,472
constexpr int kRows4 = kB * kNX * 4;          // 1600 rows (b, ix, iy-quarter)
constexpr int kCap4 = 1120;                   // mean 866, +8.6 sigma
constexpr int kOvfCap = 4096;                 // overflow list (never used)

constexpr int kTiles = kBN * (kHW / 64);      // 528 (bn, hw-tile-64)
constexpr int kFusedBlks = kTiles * 2;        // [0,528) transpose | [528,1056) binfill
}  // namespace

// Blocks fp-contraction (hipcc -ffp-contract=fast would fuse mul+sub into
// fma and change voxel binning vs the per-op f32 numpy reference).
#define FP_BARRIER(x) asm volatile("" : "+v"(x))

// f32 -> bf16 with round-to-nearest-even (bf16 = high 16 bits of f32).
__device__ __forceinline__ uint32_t f2bf_rne(float f) {
  uint32_t u = __float_as_uint(f);
  return (u + 0x7FFFu + ((u >> 16) & 1u)) >> 16;
}

// Zero cnt[kRows4] + ovf_cnt (6.4KB). ~2us in the timed graph.
__global__ void __launch_bounds__(256) lss_zero(unsigned* __restrict__ cnt) {
  for (int i = threadIdx.x; i <= kRows4; i += 256) cnt[i] = 0u;
}

// Fused kernel, block-partitioned (EXACT R18 — best measured 53.6us):
//   [0, kTiles)        : transpose feat [bn][c][hw] -> featT bf16 [bn*hw][32u32]
//   [kTiles, 2*kTiles) : per-(bn, hw-tile) softmax stats IN-BLOCK + voxel bin
//                        (proven barriered per-op f32) + row-CSR fill.
__global__ void __launch_bounds__(512) lss_fused(
    const float* __restrict__ feat, uint32_t* __restrict__ featT,
    const float* __restrict__ logits, const float* __restrict__ geom,
    unsigned* __restrict__ cnt, uint2* __restrict__ list,
    unsigned* __restrict__ ovf_cnt, uint4* __restrict__ ovf) {
  int blk = blockIdx.x;
  int tid = threadIdx.x;
  if (blk < kTiles) {
    // ---- transpose + bf16 pack ----
    __shared__ float t[64][65];
    int bn = blk / 44, hw0 = (blk % 44) * 64;
    const float* src = feat + (size_t)bn * kC * kHW;
    for (int idx = tid; idx < 64 * 64; idx += 512) {
      int c = idx >> 6, hw = idx & 63;           // consecutive tid -> hw
      t[hw][c] = src[(size_t)c * kHW + hw0 + hw];
    }
    __syncthreads();
    uint32_t* dst = featT + ((size_t)bn * kHW + hw0) * 32;
    for (int idx = tid; idx < 64 * 32; idx += 512) {
      int hw = idx >> 5, j = idx & 31;           // consecutive tid -> j
      uint32_t lo = f2bf_rne(t[hw][2 * j]);
      uint32_t hi = f2bf_rne(t[hw][2 * j + 1]);
      dst[(size_t)hw * 32 + j] = lo | (hi << 16);
    }
  } else {
    // ---- stats + bin + fill: tile (bn, hw0..hw0+63) x all d ----
    __shared__ unsigned shist[kRows4];   // 6.4K
    __shared__ unsigned sbase[kRows4];   // 6.4K
    __shared__ float smax[8 * 64];       // 2K
    __shared__ float ssum[8 * 64];       // 2K
    int tb = blk - kTiles;
    int bn = tb / 44, hw0 = (tb % 44) * 64;
    int hwl = tid & 63, dg = tid >> 6;   // 8 d-groups (waves)
    int hw = hw0 + hwl;
    int b = (bn >= kN) ? 1 : 0;
    int col = bn * kHW + hw;
    int d0 = (dg * kD) >> 3, d1 = ((dg + 1) * kD) >> 3;  // 5..6 d's each
    for (int r = tid; r < kRows4; r += 512) shist[r] = 0;
    // softmax stats (fmax exactly associative -> M identical to serial;
    // S differs ~1ulp from group-partial order -> harmless)
    float x[6];
    float m = -INFINITY;
#pragma unroll
    for (int k = 0; k < 6; ++k) {
      int d = d0 + k;
      if (d < d1) {
        x[k] = logits[(size_t)(bn * kD + d) * kHW + hw];
        m = fmaxf(m, x[k]);
      }
    }
    smax[dg * 64 + hwl] = m;
    __syncthreads();                      // also covers shist zeroing
    float M = smax[hwl];
#pragma unroll
    for (int gg = 1; gg < 8; ++gg) M = fmaxf(M, smax[gg * 64 + hwl]);
    float s = 0.0f;
#pragma unroll
    for (int k = 0; k < 6; ++k) {
      int d = d0 + k;
      if (d < d1) { x[k] = expf(x[k] - M); s += x[k]; }
    }
    ssum[dg * 64 + hwl] = s;
    __syncthreads();
    float S = ssum[hwl];
#pragma unroll
    for (int gg = 1; gg < 8; ++gg) S += ssum[gg * 64 + hwl];
    // voxel bin (proven barriered per-op f32) + per-row4 histogram
    int vv[6];
#pragma unroll
    for (int k = 0; k < 6; ++k) {
      vv[k] = -1;
      int d = d0 + k;
      if (d < d1) {
        size_t g = ((size_t)(bn * kD + d) * kHW + hw) * 3;
        float gx = geom[g + 0];
        float gy = geom[g + 1];
        float gz = geom[g + 2];
        float px = __fmul_rn(gx, 100.0f); FP_BARRIER(px);
        float py = __fmul_rn(gy, 100.0f); FP_BARRIER(py);
        float pz = __fmul_rn(gz, 20.0f);  FP_BARRIER(pz);
        float wx = __fsub_rn(px, 50.0f);  FP_BARRIER(wx);
        float wy = __fsub_rn(py, 50.0f);  FP_BARRIER(wy);
        float wz = __fsub_rn(pz, 10.0f);  FP_BARRIER(wz);
        float tx = __fadd_rn(wx, 50.0f);  FP_BARRIER(tx);
        float ty = __fadd_rn(wy, 50.0f);  FP_BARRIER(ty);
        float tz = __fadd_rn(wz, 10.0f);  FP_BARRIER(tz);
        float qx = __fdiv_rn(tx, 0.5f);   FP_BARRIER(qx);
        float qy = __fdiv_rn(ty, 0.5f);   FP_BARRIER(qy);
        float qz = __fdiv_rn(tz, 20.0f);  FP_BARRIER(qz);
        int ix = (int)floorf(qx);
        int iy = (int)floorf(qy);
        int iz = (int)floorf(qz);
        if ((unsigned)ix < (unsigned)kNX && (unsigned)iy < (unsigned)kNX &&
            (unsigned)iz < 1u) {
          vv[k] = (ix << 8) | iy;
          atomicAdd(&shist[((b * kNX + ix) << 2) + iy / 50], 1u);
        }
      }
    }
    __syncthreads();
    for (int r = tid; r < kRows4; r += 512)
      if (shist[r]) sbase[r] = atomicAdd(&cnt[r], shist[r]);
    __syncthreads();
    // scatter entries {iy|col, wgt} into fixed row segments (line-dense)
#pragma unroll
    for (int k = 0; k < 6; ++k) {
      if (vv[k] < 0) continue;
      int ix = vv[k] >> 8, iy = vv[k] & 255;
      int row4 = ((b * kNX + ix) << 2) + iy / 50;
      float wgt = x[k] / S;
      unsigned key = ((unsigned)iy << 16) | (unsigned)col;
      unsigned pos = atomicAdd(&sbase[row4], 1u);  // LDS cursor
      if (pos < (unsigned)kCap4) {
        list[(size_t)row4 * kCap4 + pos] =
            make_uint2(key, __float_as_uint(wgt));
      } else {                                     // never (+8.6 sigma)
        unsigned o = atomicAdd(ovf_cnt, 1u);
        if (o < (unsigned)kOvfCap)
          ovf[o] = make_uint4((unsigned)row4, key, __float_as_uint(wgt), 0u);
      }
    }
  }
}

// Row gather: EXACT R18 v5 (best measured). 512 threads per
// (b, ix, iy-quarter); XCD swizzle; single global pass (slr stash +
// wave-0 shfl scan); 8-lane group per bin, uint4 loads, 4-deep unroll.
__global__ void __launch_bounds__(512) lss_rowgather(
    const unsigned* __restrict__ cnt, const uint2* __restrict__ list,
    const uint32_t* __restrict__ featT, float* __restrict__ out,
    const unsigned* __restrict__ ovf_cnt, const uint4* __restrict__ ovf) {
  __shared__ uint2 slr[kCap4];          // 8.96 KB raw entries (arrival order)
  __shared__ uint2 sl[kCap4];           // 8.96 KB sorted entries
  __shared__ float accT[50 * 65];       // 13.0 KB (pad 65: store bank-free)
  __shared__ unsigned hist[64];
  __shared__ unsigned off[51];
  __shared__ unsigned curb[50];
  int tid = threadIdx.x;
  // XCD swizzle: bijective (kRows4 % 8 == 0); XCD x gets r4 in [x*200,(x+1)*200)
  int r4 = ((blockIdx.x & 7) * (kRows4 / 8)) + (blockIdx.x >> 3);
  int q = r4 & 3;
  int r = r4 >> 2;
  int b = r / kNX, ix = r - (r / kNX) * kNX;
  int iyb = q * 50;
  size_t s0 = (size_t)r4 * kCap4;
  unsigned n = cnt[r4];
  unsigned ns = min(n, (unsigned)kCap4);

  if (tid < 64) hist[tid] = 0;
  __syncthreads();
  // pass 1: stash + histogram (single global read of the row's entries)
  for (unsigned k = tid; k < ns; k += 512) {
    uint2 a = list[s0 + k];
    slr[k] = a;
    atomicAdd(&hist[(a.x >> 16) - iyb], 1u);
  }
  __syncthreads();
  // wave-0 inclusive scan over 64 bins (no block barriers inside)
  if (tid < 64) {
    unsigned v = hist[tid];
    unsigned sc = v;
#pragma unroll
    for (int o = 1; o < 64; o <<= 1) {
      unsigned y = __shfl_up(sc, o);
      if (tid >= o) sc += y;
    }
    if (tid < 50) {
      off[tid] = sc - v;
      curb[tid] = sc - v;
    }
    if (tid == 0) off[50] = ns;
  }
  __syncthreads();
  // pass 2: reorder LDS -> LDS (no second global read)
  for (unsigned k = tid; k < ns; k += 512) {
    uint2 a = slr[k];
    unsigned pos = atomicAdd(&curb[(a.x >> 16) - iyb], 1u);
    sl[pos] = a;
  }
  __syncthreads();
  // accumulate: group ly = tid>>3 owns bin ly; lane sub = tid&7 owns
  // channels sub*8..sub*8+7 (uint4 = 4 u32 = 8 bf16)
  int ly = tid >> 3, sub = tid & 7;
  if (ly < 50) {
    unsigned k = off[ly], e = off[ly + 1];
    float a0 = 0, a1 = 0, a2 = 0, a3 = 0, a4 = 0, a5 = 0, a6 = 0, a7 = 0;
    for (; k + 4 <= e; k += 4) {        // 4 entries -> 4 lines in flight
      uint2 e0 = sl[k + 0];
      uint2 e1 = sl[k + 1];
      uint2 e2 = sl[k + 2];
      uint2 e3 = sl[k + 3];
      uint4 f0 = ((const uint4*)(featT + ((size_t)(e0.x & 0xFFFFu) << 5)))[sub];
      uint4 f1 = ((const uint4*)(featT + ((size_t)(e1.x & 0xFFFFu) << 5)))[sub];
      uint4 f2 = ((const uint4*)(featT + ((size_t)(e2.x & 0xFFFFu) << 5)))[sub];
      uint4 f3 = ((const uint4*)(featT + ((size_t)(e3.x & 0xFFFFu) << 5)))[sub];
      float w0 = __uint_as_float(e0.y), w1 = __uint_as_float(e1.y);
      float w2 = __uint_as_float(e2.y), w3 = __uint_as_float(e3.y);
      a0 += w0 * __uint_as_float(f0.x << 16);
      a1 += w0 * __uint_as_float(f0.x & 0xFFFF0000u);
      a2 += w0 * __uint_as_float(f0.y << 16);
      a3 += w0 * __uint_as_float(f0.y & 0xFFFF0000u);
      a4 += w0 * __uint_as_float(f0.z << 16);
      a5 += w0 * __uint_as_float(f0.z & 0xFFFF0000u);
      a6 += w0 * __uint_as_float(f0.w << 16);
      a7 += w0 * __uint_as_float(f0.w & 0xFFFF0000u);
      a0 += w1 * __uint_as_float(f1.x << 16);
      a1 += w1 * __uint_as_float(f1.x & 0xFFFF0000u);
      a2 += w1 * __uint_as_float(f1.y << 16);
      a3 += w1 * __uint_as_float(f1.y & 0xFFFF0000u);
      a4 += w1 * __uint_as_float(f1.z << 16);
      a5 += w1 * __uint_as_float(f1.z & 0xFFFF0000u);
      a6 += w1 * __uint_as_float(f1.w << 16);
      a7 += w1 * __uint_as_float(f1.w & 0xFFFF0000u);
      a0 += w2 * __uint_as_float(f2.x << 16);
      a1 += w2 * __uint_as_float(f2.x & 0xFFFF0000u);
      a2 += w2 * __uint_as_float(f2.y << 16);
      a3 += w2 * __uint_as_float(f2.y & 0xFFFF0000u);
      a4 += w2 * __uint_as_float(f2.z << 16);
      a5 += w2 * __uint_as_float(f2.z & 0xFFFF0000u);
      a6 += w2 * __uint_as_float(f2.w << 16);
      a7 += w2 * __uint_as_float(f2.w & 0xFFFF0000u);
      a0 += w3 * __uint_as_float(f3.x << 16);
      a1 += w3 * __uint_as_float(f3.x & 0xFFFF0000u);
      a2 += w3 * __uint_as_float(f3.y << 16);
      a3 += w3 * __uint_as_float(f3.y & 0xFFFF0000u);
      a4 += w3 * __uint_as_float(f3.z << 16);
      a5 += w3 * __uint_as_float(f3.z & 0xFFFF0000u);
      a6 += w3 * __uint_as_float(f3.w << 16);
      a7 += w3 * __uint_as_float(f3.w & 0xFFFF0000u);
    }
    for (; k < e; ++k) {
      uint2 ea = sl[k];
      uint4 fa = ((const uint4*)(featT + ((size_t)(ea.x & 0xFFFFu) << 5)))[sub];
      float wa = __uint_as_float(ea.y);
      a0 += wa * __uint_as_float(fa.x << 16);
      a1 += wa * __uint_as_float(fa.x & 0xFFFF0000u);
      a2 += wa * __uint_as_float(fa.y << 16);
      a3 += wa * __uint_as_float(fa.y & 0xFFFF0000u);
      a4 += wa * __uint_as_float(fa.z << 16);
      a5 += wa * __uint_as_float(fa.z & 0xFFFF0000u);
      a6 += wa * __uint_as_float(fa.w << 16);
      a7 += wa * __uint_as_float(fa.w & 0xFFFF0000u);
    }
    float* dst = &accT[ly * 65 + (sub << 3)];
    dst[0] = a0; dst[1] = a1; dst[2] = a2; dst[3] = a3;
    dst[4] = a4; dst[5] = a5; dst[6] = a6; dst[7] = a7;
  }
  __syncthreads();
  // overflow epilogue (never taken; kept for correctness)
  unsigned ovfn = min(*ovf_cnt, (unsigned)kOvfCap);
  if (ovfn > 0) {
    for (unsigned k = tid; k < ovfn; k += 512) {
      uint4 a = ovf[k];
      if (a.x != (unsigned)r4) continue;
      int lyo = (int)(a.y >> 16) - iyb;
      const uint32_t* fr = featT + ((size_t)(a.y & 0xFFFFu) << 5);
      float w = __uint_as_float(a.z);
      for (int c = 0; c < kC; ++c) {
        uint32_t u = fr[c >> 1];
        float f = __uint_as_float((c & 1) ? (u & 0xFFFF0000u) : (u << 16));
        atomicAdd(&accT[lyo * 65 + c], w * f);
      }
    }
    __syncthreads();
  }
  // coalesced tile store (every cell written -> no output memset)
  float* op = out + (size_t)b * kC * kVox + (size_t)ix * kNX + iyb;
  for (int idx = tid; idx < kC * 50; idx += 512) {
    int c = idx / 50, iy = idx - c * 50;
    op[(size_t)c * kVox + iy] = accT[iy * 65 + c];
  }
}

extern "C" void kernel_launch(void* const* d_in, const int* in_sizes, int n_in,
                              void* d_out, int out_size, void* d_ws,
                              size_t ws_size, hipStream_t stream) {
  const float* feat = (const float*)d_in[0];
  const float* logits = (const float*)d_in[1];
  const float* geom = (const float*)d_in[2];
  float* out = (float*)d_out;

  // Workspace layout (16B-aligned chunks): total ~18.7 MB
  char* w = (char*)d_ws;
  uint2* list = (uint2*)w;         w += (size_t)kRows4 * kCap4 * 8;  // 14.34MB
  uint32_t* featT = (uint32_t*)w;  w += (size_t)kBN * kHW * 32 * 4;  // 4.33MB
  uint4* ovf = (uint4*)w;          w += (size_t)kOvfCap * 16;        // 64KB
  unsigned* cnt = (unsigned*)w;    w += (size_t)kRows4 * 4;
  // ovf_cnt = cnt[kRows4] (zeroed together by lss_zero)
  unsigned* ovf_cnt = cnt + kRows4;

  lss_zero<<<1, 256, 0, stream>>>(cnt);
  lss_fused<<<kFusedBlks, 512, 0, stream>>>(feat, featT, logits, geom, cnt,
                                            list, ovf_cnt, ovf);
  lss_rowgather<<<kRows4, 512, 0, stream>>>(cnt, list, featT, out, ovf_cnt,
                                            ovf);
}